// Round 8
// baseline (3838.337 us; speedup 1.0000x reference)
//
#include <hip/hip_runtime.h>
#include <math.h>

// Problem constants (fixed by reference file)
#define NB   512    // N = batch of user pairs
#define MM   254    // M uav nodes
#define SS   256    // S = M + 2 graph nodes per b
#define HH   128    // H hidden
#define RTOT 1278   // 2N + M rows in `outputs`

__device__ __forceinline__ float sigm(float x)   { return 1.0f / (1.0f + __expf(-x)); }
__device__ __forceinline__ float tanh_f(float x) { return 1.0f - 2.0f / (1.0f + __expf(2.0f * x)); }

// Per node row r: e = pos @ W_embed + b_embed (128),
//   EWi[r][j]   = (e @ lstm_Wi)[j] + lstm_b[j]   (bias folded; j coalesced)
//   W1eP[h2][r] = float2(W1e[2h2], W1e[2h2+1])   (lane-coalesced over r)
__global__ __launch_bounds__(128) void precompute_k(
    const float* __restrict__ outputs, const float* __restrict__ Wemb,
    const float* __restrict__ bemb, const float* __restrict__ Wi,
    const float* __restrict__ W1, const float* __restrict__ lb,
    float* __restrict__ EWi, float2* __restrict__ W1eP)
{
  int r = blockIdx.x;
  int t = threadIdx.x;  // 128
  __shared__ float e[HH];
  __shared__ float w1e[HH];
  float px = outputs[2 * r], py = outputs[2 * r + 1];
  e[t] = px * Wemb[t] + py * Wemb[HH + t] + bemb[t];
  __syncthreads();
  float acc = 0.f;
#pragma unroll 8
  for (int h = 0; h < HH; ++h) acc = fmaf(e[h], W1[h * HH + t], acc);
  w1e[t] = acc;
#pragma unroll
  for (int c = 0; c < 4; ++c) {
    int j = t + c * HH;
    float a = 0.f;
#pragma unroll 8
    for (int h = 0; h < HH; ++h) a = fmaf(e[h], Wi[h * 512 + j], a);
    EWi[(size_t)r * 512 + j] = a + lb[j];
  }
  __syncthreads();
  if (t < 64) {
    float2 p; p.x = w1e[2 * t]; p.y = w1e[2 * t + 1];
    W1eP[(size_t)t * RTOT + r] = p;
  }
}

// One block per batch element b. 512 threads (8 waves). Grid 512 ->
// 2 independent blocks per CU: their barrier schedules interleave, so one
// block's VALU fills the other's latency/barrier stalls (the round-4
// single-block lockstep had nothing to fill them with).
__global__ __launch_bounds__(512) void decode_k(
    const float* __restrict__ outputs, const float* __restrict__ Wh,
    const float* __restrict__ W2, const float* __restrict__ av,
    const float* __restrict__ EWi, const float2* __restrict__ W1eP,
    float* __restrict__ maxd_out)
{
  const int t = threadIdx.x;   // 0..511
  const int b = blockIdx.x;    // one batch element per block

  __shared__ float posS[2 * RTOT];   // 10.2 KB: all node positions
  __shared__ float hS[HH];
  __shared__ float gS[512];
  __shared__ float qpS[4][HH];
  __shared__ float qS[HH], vS[HH];
  __shared__ float lp[2][SS];        // logit partials [hhalf][u]
  __shared__ int   lsS[SS];          // node id s per slot u
  __shared__ int   actS[254];
  __shared__ int   cntS, curS;

  for (int i = t; i < 2 * RTOT; i += 512) posS[i] = outputs[i];
  if (t < HH) { hS[t] = 0.f; vS[t] = av[t]; }
  if (t < 254) actS[t] = t + 1;      // s = 1..254 initially active
  if (t == 0) { cntS = 254; curS = b; }
  __syncthreads();

  float px = 0.f, py = 0.f, md = 0.f;   // live only in t==0
  if (t == 0) { px = posS[2 * b]; py = posS[2 * b + 1]; }

  float creg = 0.f;                     // LSTM c-state, owned by t<128

  const int qj = t & 127, qq = t >> 7;  // q-phase split
  const int lu = t & 255, lh = t >> 8;  // logits split

  for (int k = 0; k < SS; ++k) {
    int cur = curS;
    int cnt = cntS;
    int cntEff = cnt + (k > 0 ? 1 : 0); // dst node (255) re-enters for k>0

    // ---- Phase A: gates[t] = EWi[cur][t] + sum_kk h[kk]*Wh[kk][t]
    // EWi load issued first (latency hides under the FMA stream).
    {
      float ew = EWi[(size_t)cur * 512 + t];
      const float* wp = Wh + t;
      float a0 = 0.f, a1 = 0.f, a2 = 0.f, a3 = 0.f;
#pragma unroll 2
      for (int kk = 0; kk < HH; kk += 4) {   // ~8 loads in flight
        a0 = fmaf(hS[kk + 0], wp[(size_t)(kk + 0) * 512], a0);
        a1 = fmaf(hS[kk + 1], wp[(size_t)(kk + 1) * 512], a1);
        a2 = fmaf(hS[kk + 2], wp[(size_t)(kk + 2) * 512], a2);
        a3 = fmaf(hS[kk + 3], wp[(size_t)(kk + 3) * 512], a3);
      }
      gS[t] = ew + (a0 + a1) + (a2 + a3);
    }
    __syncthreads();  // B1

    // ---- Phase B: LSTM cell (t<128; order i,f,g,o)
    if (t < HH) {
      float iv = sigm(gS[t]);
      float fv = sigm(gS[HH + t]);
      float gv = tanh_f(gS[2 * HH + t]);
      float ov = sigm(gS[3 * HH + t]);
      float cn = fv * creg + iv * gv;
      creg = cn;
      hS[t] = ov * tanh_f(cn);
    }
    __syncthreads();  // B2

    // ---- Phase C: q partials, 4-way K-split
    {
      const float* wp = W2 + (size_t)(qq * 32) * HH + qj;
      const float* hp = &hS[qq * 32];
      float p0 = 0.f, p1 = 0.f;
#pragma unroll 4
      for (int kk = 0; kk < 32; kk += 2) {
        p0 = fmaf(hp[kk],     wp[(size_t)kk * HH],       p0);
        p1 = fmaf(hp[kk + 1], wp[(size_t)(kk + 1) * HH], p1);
      }
      qpS[qq][qj] = p0 + p1;
    }
    __syncthreads();  // B3

    // ---- Phase D: q reduce (t<128)
    if (t < HH)
      qS[t] = (qpS[0][t] + qpS[1][t]) + (qpS[2][t] + qpS[3][t]);
    __syncthreads();  // B4

    // ---- Phase E: logits over active nodes, 2-way h-split
    if (lu < cntEff) {
      int s = (lu == cnt) ? 255 : actS[lu];
      int r = (s == 255) ? (NB + b) : (2 * NB + s - 1);
      const float2* wp = W1eP + (size_t)(lh * 32) * RTOT + r;
      const float* qv = &qS[lh * 64];   // wave-uniform => LDS broadcast
      const float* vv = &vS[lh * 64];
      float c0 = 0.f, c1 = 0.f;
#pragma unroll 4
      for (int i = 0; i < 32; ++i) {
        float2 w = wp[(size_t)i * RTOT];
        c0 = fmaf(vv[2 * i],     tanh_f(w.x + qv[2 * i]),     c0);
        c1 = fmaf(vv[2 * i + 1], tanh_f(w.y + qv[2 * i + 1]), c1);
      }
      lp[lh][lu] = c0 + c1;
      if (lh == 0) lsS[lu] = s;
    }
    __syncthreads();  // B5

    // ---- Phase F: argmax (wave 0) + state update (t==0)
    if (t < 64) {
      float val = -INFINITY;
      unsigned key = 0xFFFFFFFFu;
#pragma unroll
      for (int c = 0; c < 4; ++c) {
        int u = t + 64 * c;
        if (u < cntEff) {
          float v2 = lp[0][u] + lp[1][u];
          unsigned k2 = ((unsigned)lsS[u] << 16) | (unsigned)u;
          if (v2 > val || (v2 == val && k2 < key)) { val = v2; key = k2; }
        }
      }
#pragma unroll
      for (int off = 1; off < 64; off <<= 1) {
        float v2 = __shfl_xor(val, off);
        unsigned k2 = __shfl_xor(key, off);
        if (v2 > val || (v2 == val && k2 < key)) { val = v2; key = k2; }
      }
      if (t == 0) {
        int s   = (int)(key >> 16);
        int pos = (int)(key & 0xFFFFu);
        int rn  = (s == 255) ? (NB + b) : (2 * NB + s - 1);
        float nx = posS[2 * rn], ny = posS[2 * rn + 1];
        float dx = nx - px, dy = ny - py;
        float d = sqrtf(dx * dx + dy * dy + 1e-12f);
        if (d > md) md = d;
        px = nx; py = ny;
        curS = rn;
        if (s != 255) { actS[pos] = actS[cnt - 1]; cntS = cnt - 1; }
      }
    }
    __syncthreads();  // B6
  }

  if (t == 0) maxd_out[b] = md;
}

__global__ __launch_bounds__(512) void reduce_k(const float* __restrict__ maxd,
                                               float* __restrict__ out)
{
  __shared__ float s[512];
  int t = threadIdx.x;
  s[t] = maxd[t];
  __syncthreads();
  for (int off = 256; off > 0; off >>= 1) {
    if (t < off) s[t] += s[t + off];
    __syncthreads();
  }
  if (t == 0) out[0] = s[0] * (1.0f / 512.0f);
}

extern "C" void kernel_launch(void* const* d_in, const int* in_sizes, int n_in,
                              void* d_out, int out_size, void* d_ws, size_t ws_size,
                              hipStream_t stream) {
  const float* outputs = (const float*)d_in[0];
  const float* Wemb    = (const float*)d_in[1];
  const float* bemb    = (const float*)d_in[2];
  const float* Wi      = (const float*)d_in[3];
  const float* Wh      = (const float*)d_in[4];
  const float* lb      = (const float*)d_in[5];
  const float* W1      = (const float*)d_in[6];
  const float* W2      = (const float*)d_in[7];
  const float* av      = (const float*)d_in[8];
  // d_in[9] = N (known constant 512)

  float* ws    = (float*)d_ws;
  float*  EWi  = ws;                                      // 1278*512 floats
  float2* W1eP = (float2*)(ws + (size_t)RTOT * 512);      // 64*1278 float2
  float*  maxd = ws + (size_t)RTOT * 512 + (size_t)HH * RTOT;  // 512

  hipLaunchKernelGGL(precompute_k, dim3(RTOT), dim3(HH), 0, stream,
                     outputs, Wemb, bemb, Wi, W1, lb, EWi, W1eP);
  hipLaunchKernelGGL(decode_k, dim3(NB), dim3(512), 0, stream,
                     outputs, Wh, W2, av, EWi, W1eP, maxd);
  hipLaunchKernelGGL(reduce_k, dim3(1), dim3(512), 0, stream, maxd, (float*)d_out);
}

// Round 9
// 3610.325 us; speedup vs baseline: 1.0632x; 1.0632x over previous
//
#include <hip/hip_runtime.h>
#include <math.h>

// Problem constants (fixed by reference file)
#define NB   512    // N = batch of user pairs
#define MM   254    // M uav nodes
#define SS   256    // S = M + 2 graph nodes per b
#define HH   128    // H hidden
#define RTOT 1278   // 2N + M rows in `outputs`

__device__ __forceinline__ float sigm(float x)   { return 1.0f / (1.0f + __expf(-x)); }
__device__ __forceinline__ float tanh_f(float x) { return 1.0f - 2.0f / (1.0f + __expf(2.0f * x)); }

// Per node row r: e = pos @ W_embed + b_embed (128),
//   EWi[r][j]    = (e @ lstm_Wi)[j] + lstm_b[j]  (bias folded; j coalesced)
//   W1eQ[h4][r]  = float4(W1e[4h4..4h4+3])       (lane-coalesced over r)
__global__ __launch_bounds__(128) void precompute_k(
    const float* __restrict__ outputs, const float* __restrict__ Wemb,
    const float* __restrict__ bemb, const float* __restrict__ Wi,
    const float* __restrict__ W1, const float* __restrict__ lb,
    float* __restrict__ EWi, float4* __restrict__ W1eQ)
{
  int r = blockIdx.x;
  int t = threadIdx.x;  // 128
  __shared__ float e[HH];
  __shared__ float w1e[HH];
  float px = outputs[2 * r], py = outputs[2 * r + 1];
  e[t] = px * Wemb[t] + py * Wemb[HH + t] + bemb[t];
  __syncthreads();
  float acc = 0.f;
#pragma unroll 8
  for (int h = 0; h < HH; ++h) acc = fmaf(e[h], W1[h * HH + t], acc);
  w1e[t] = acc;
#pragma unroll
  for (int c = 0; c < 4; ++c) {
    int j = t + c * HH;
    float a = 0.f;
#pragma unroll 8
    for (int h = 0; h < HH; ++h) a = fmaf(e[h], Wi[h * 512 + j], a);
    EWi[(size_t)r * 512 + j] = a + lb[j];
  }
  __syncthreads();
  if (t < 32) {
    float4 p;
    p.x = w1e[4 * t]; p.y = w1e[4 * t + 1];
    p.z = w1e[4 * t + 2]; p.w = w1e[4 * t + 3];
    W1eQ[(size_t)t * RTOT + r] = p;
  }
}

// One block per batch element b. 512 threads (8 waves). Grid 512 ->
// 2 independent blocks per CU. All LDS broadcast streams are float4
// (ds_read_b128): 4x fewer LDS-pipe instructions than scalar reads.
__global__ __launch_bounds__(512) void decode_k(
    const float* __restrict__ outputs, const float* __restrict__ Wh,
    const float* __restrict__ W2, const float* __restrict__ av,
    const float* __restrict__ EWi, const float4* __restrict__ W1eQ,
    float* __restrict__ maxd_out)
{
  const int t = threadIdx.x;   // 0..511
  const int b = blockIdx.x;    // one batch element per block

  __shared__ float posS[2 * RTOT];   // 10.2 KB: all node positions
  __shared__ __align__(16) float hS[HH];
  __shared__ __align__(16) float qS[HH];
  __shared__ __align__(16) float vS[HH];
  __shared__ float gS[512];
  __shared__ __align__(16) float qpS[4][HH];
  __shared__ float lp[2][SS];        // logit partials [hhalf][u]
  __shared__ int   lsS[SS];          // node id s per slot u
  __shared__ int   actS[254];
  __shared__ int   cntS, curS;

  for (int i = t; i < 2 * RTOT; i += 512) posS[i] = outputs[i];
  if (t < HH) { hS[t] = 0.f; vS[t] = av[t]; }
  if (t < 254) actS[t] = t + 1;      // s = 1..254 initially active
  if (t == 0) { cntS = 254; curS = b; }
  __syncthreads();

  float px = 0.f, py = 0.f, md = 0.f;   // live only in t==0
  if (t == 0) { px = posS[2 * b]; py = posS[2 * b + 1]; }

  float creg = 0.f;                     // LSTM c-state, owned by t<128

  const int qj = t & 127, qq = t >> 7;  // q-phase split
  const int lu = t & 255, lh = t >> 8;  // logits split

  for (int k = 0; k < SS; ++k) {
    int cur = curS;
    int cnt = cntS;
    int cntEff = cnt + (k > 0 ? 1 : 0); // dst node (255) re-enters for k>0

    // ---- Phase A: gates[t] = EWi[cur][t] + sum_kk h[kk]*Wh[kk][t]
    {
      float ew = EWi[(size_t)cur * 512 + t];
      const float* wp = Wh + t;
      const float4* h4 = (const float4*)hS;
      float a0 = 0.f, a1 = 0.f, a2 = 0.f, a3 = 0.f;
#pragma unroll 2
      for (int i = 0; i < 32; ++i) {     // 8 global loads in flight
        float4 h = h4[i];
        a0 = fmaf(h.x, wp[(size_t)(4 * i + 0) * 512], a0);
        a1 = fmaf(h.y, wp[(size_t)(4 * i + 1) * 512], a1);
        a2 = fmaf(h.z, wp[(size_t)(4 * i + 2) * 512], a2);
        a3 = fmaf(h.w, wp[(size_t)(4 * i + 3) * 512], a3);
      }
      gS[t] = ew + (a0 + a1) + (a2 + a3);
    }
    __syncthreads();  // B1

    // ---- Phase B: LSTM cell (t<128; order i,f,g,o)
    if (t < HH) {
      float iv = sigm(gS[t]);
      float fv = sigm(gS[HH + t]);
      float gv = tanh_f(gS[2 * HH + t]);
      float ov = sigm(gS[3 * HH + t]);
      float cn = fv * creg + iv * gv;
      creg = cn;
      hS[t] = ov * tanh_f(cn);
    }
    __syncthreads();  // B2

    // ---- Phase C: q partials, 4-way K-split (float4 h broadcast)
    {
      const float* wp = W2 + (size_t)(qq * 32) * HH + qj;
      const float4* hp4 = (const float4*)(&hS[qq * 32]);
      float p0 = 0.f, p1 = 0.f;
#pragma unroll 2
      for (int i = 0; i < 8; ++i) {
        float4 h = hp4[i];
        p0 = fmaf(h.x, wp[(size_t)(4 * i + 0) * HH], p0);
        p1 = fmaf(h.y, wp[(size_t)(4 * i + 1) * HH], p1);
        p0 = fmaf(h.z, wp[(size_t)(4 * i + 2) * HH], p0);
        p1 = fmaf(h.w, wp[(size_t)(4 * i + 3) * HH], p1);
      }
      qpS[qq][qj] = p0 + p1;
    }
    __syncthreads();  // B3

    // ---- Phase D: q reduce (t<128)
    if (t < HH)
      qS[t] = (qpS[0][t] + qpS[1][t]) + (qpS[2][t] + qpS[3][t]);
    __syncthreads();  // B4

    // ---- Phase E: logits over active nodes, 2-way h-split (float4 streams)
    if (lu < cntEff) {
      int s = (lu == cnt) ? 255 : actS[lu];
      int r = (s == 255) ? (NB + b) : (2 * NB + s - 1);
      const float4* wp = W1eQ + (size_t)(lh * 16) * RTOT + r;
      const float4* qv4 = (const float4*)(&qS[lh * 64]);
      const float4* vv4 = (const float4*)(&vS[lh * 64]);
      float c0 = 0.f, c1 = 0.f;
#pragma unroll 4
      for (int i = 0; i < 16; ++i) {
        float4 w = wp[(size_t)i * RTOT];
        float4 q = qv4[i];
        float4 v = vv4[i];
        c0 = fmaf(v.x, tanh_f(w.x + q.x), c0);
        c1 = fmaf(v.y, tanh_f(w.y + q.y), c1);
        c0 = fmaf(v.z, tanh_f(w.z + q.z), c0);
        c1 = fmaf(v.w, tanh_f(w.w + q.w), c1);
      }
      lp[lh][lu] = c0 + c1;
      if (lh == 0) lsS[lu] = s;
    }
    __syncthreads();  // B5

    // ---- Phase F: argmax (wave 0) + state update (t==0)
    if (t < 64) {
      float val = -INFINITY;
      unsigned key = 0xFFFFFFFFu;
#pragma unroll
      for (int c = 0; c < 4; ++c) {
        int u = t + 64 * c;
        if (u < cntEff) {
          float v2 = lp[0][u] + lp[1][u];
          unsigned k2 = ((unsigned)lsS[u] << 16) | (unsigned)u;
          if (v2 > val || (v2 == val && k2 < key)) { val = v2; key = k2; }
        }
      }
#pragma unroll
      for (int off = 1; off < 64; off <<= 1) {
        float v2 = __shfl_xor(val, off);
        unsigned k2 = __shfl_xor(key, off);
        if (v2 > val || (v2 == val && k2 < key)) { val = v2; key = k2; }
      }
      if (t == 0) {
        int s   = (int)(key >> 16);
        int pos = (int)(key & 0xFFFFu);
        int rn  = (s == 255) ? (NB + b) : (2 * NB + s - 1);
        float nx = posS[2 * rn], ny = posS[2 * rn + 1];
        float dx = nx - px, dy = ny - py;
        float d = sqrtf(dx * dx + dy * dy + 1e-12f);
        if (d > md) md = d;
        px = nx; py = ny;
        curS = rn;
        if (s != 255) { actS[pos] = actS[cnt - 1]; cntS = cnt - 1; }
      }
    }
    __syncthreads();  // B6
  }

  if (t == 0) maxd_out[b] = md;
}

__global__ __launch_bounds__(512) void reduce_k(const float* __restrict__ maxd,
                                               float* __restrict__ out)
{
  __shared__ float s[512];
  int t = threadIdx.x;
  s[t] = maxd[t];
  __syncthreads();
  for (int off = 256; off > 0; off >>= 1) {
    if (t < off) s[t] += s[t + off];
    __syncthreads();
  }
  if (t == 0) out[0] = s[0] * (1.0f / 512.0f);
}

extern "C" void kernel_launch(void* const* d_in, const int* in_sizes, int n_in,
                              void* d_out, int out_size, void* d_ws, size_t ws_size,
                              hipStream_t stream) {
  const float* outputs = (const float*)d_in[0];
  const float* Wemb    = (const float*)d_in[1];
  const float* bemb    = (const float*)d_in[2];
  const float* Wi      = (const float*)d_in[3];
  const float* Wh      = (const float*)d_in[4];
  const float* lb      = (const float*)d_in[5];
  const float* W1      = (const float*)d_in[6];
  const float* W2      = (const float*)d_in[7];
  const float* av      = (const float*)d_in[8];
  // d_in[9] = N (known constant 512)

  float* ws    = (float*)d_ws;
  float*  EWi  = ws;                                      // 1278*512 floats
  float4* W1eQ = (float4*)(ws + (size_t)RTOT * 512);      // 32*1278 float4
  float*  maxd = ws + (size_t)RTOT * 512 + (size_t)HH * RTOT;  // 512

  hipLaunchKernelGGL(precompute_k, dim3(RTOT), dim3(HH), 0, stream,
                     outputs, Wemb, bemb, Wi, W1, lb, EWi, W1eQ);
  hipLaunchKernelGGL(decode_k, dim3(NB), dim3(512), 0, stream,
                     outputs, Wh, W2, av, EWi, W1eQ, maxd);
  hipLaunchKernelGGL(reduce_k, dim3(1), dim3(512), 0, stream, maxd, (float*)d_out);
}

// Round 10
// 3190.741 us; speedup vs baseline: 1.2030x; 1.1315x over previous
//
#include <hip/hip_runtime.h>
#include <math.h>

// Problem constants (fixed by reference file)
#define NB   512    // N = batch of user pairs
#define MM   254    // M uav nodes
#define SS   256    // S = M + 2 graph nodes per b
#define HH   128    // H hidden
#define RTOT 1278   // 2N + M rows in `outputs`
#define NBLK 256    // decode blocks; each handles b and b+256

__device__ __forceinline__ float sigm(float x)   { return 1.0f / (1.0f + __expf(-x)); }
__device__ __forceinline__ float tanh_f(float x) { return 1.0f - 2.0f / (1.0f + __expf(2.0f * x)); }

// Per node row r: e = pos @ W_embed + b_embed (128),
//   EWiP[r][j] = float4(i,f,g,o) columns of e@lstm_Wi + lstm_b  (bias folded)
//   W1eQ[h4][r] = float4(W1e[4h4..4h4+3])  (lane-coalesced over r)
__global__ __launch_bounds__(128) void precompute_k(
    const float* __restrict__ outputs, const float* __restrict__ Wemb,
    const float* __restrict__ bemb, const float* __restrict__ Wi,
    const float* __restrict__ W1, const float* __restrict__ lb,
    float4* __restrict__ EWiP, float4* __restrict__ W1eQ)
{
  int r = blockIdx.x;
  int t = threadIdx.x;  // 128
  __shared__ float e[HH];
  __shared__ float w1e[HH];
  float px = outputs[2 * r], py = outputs[2 * r + 1];
  e[t] = px * Wemb[t] + py * Wemb[HH + t] + bemb[t];
  __syncthreads();
  float acc = 0.f;
#pragma unroll 8
  for (int h = 0; h < HH; ++h) acc = fmaf(e[h], W1[h * HH + t], acc);
  w1e[t] = acc;
  float g4[4];
#pragma unroll
  for (int c = 0; c < 4; ++c) {
    int j = t + c * HH;
    float a = 0.f;
#pragma unroll 8
    for (int h = 0; h < HH; ++h) a = fmaf(e[h], Wi[h * 512 + j], a);
    g4[c] = a + lb[j];
  }
  float4 v4; v4.x = g4[0]; v4.y = g4[1]; v4.z = g4[2]; v4.w = g4[3];
  EWiP[(size_t)r * HH + t] = v4;
  __syncthreads();
  if (t < 32) {
    float4 p;
    p.x = w1e[4 * t]; p.y = w1e[4 * t + 1];
    p.z = w1e[4 * t + 2]; p.w = w1e[4 * t + 3];
    W1eQ[(size_t)t * RTOT + r] = p;
  }
}

// One block per TWO batch elements (b, b+256). 1024 threads, grid 256.
// Wh rows 64..127 live in LDS (128 KB -> 1 block/CU -> 128-VGPR budget).
// Phase A: 32 global loads/thread (2x16 bursts) + 32 LDS w-reads, shared by
// both b's. All h/q/v broadcast reads are float4 (wave-uniform => free).
__global__ __launch_bounds__(1024) void decode_k(
    const float* __restrict__ outputs, const float* __restrict__ Wh,
    const float* __restrict__ W2, const float* __restrict__ av,
    const float4* __restrict__ EWiP, const float4* __restrict__ W1eQ,
    float* __restrict__ maxd_out)
{
  const int t = threadIdx.x;   // 0..1023
  const int bid = blockIdx.x;

  __shared__ float WhL[64][512];            // 128 KB: Wh rows 64..127
  __shared__ float posU[2 * MM];            // uav node positions (2 KB)
  __shared__ float dstS[2][2];              // per-g dst node position
  __shared__ __align__(16) float hS[2][HH];
  __shared__ __align__(16) float qS[2][HH];
  __shared__ __align__(16) float vS[HH];
  __shared__ float pS[2][2][512];           // gates partials [g][gh][j] (8 KB)
  __shared__ float qp[2][8][HH];            // q partials [g][slice][j] (8 KB)
  __shared__ float lp[2][2][SS];            // logit partials [g][hhalf][u] (4 KB)
  __shared__ int   lsS[2][SS];              // node id s per slot u
  __shared__ int   actS[2][254];
  __shared__ int   cntS[2], curS[2];

  const int gj  = t & 511;       // gates column
  const int gh  = t >> 9;        // gates half (0/1)
  const int qj  = t & 127;       // q column
  const int qq8 = t >> 7;        // q k-slice (0..7)
  const int lg  = t >> 9;        // logits batch slot
  const int lhf = (t >> 8) & 1;  // logits h-half
  const int lu  = t & 255;       // logits node slot

  // ---- init: stage WhL (rows 64..127), posU, state ----
  for (int i = t; i < 64 * 512; i += 1024) ((float*)WhL)[i] = Wh[64 * 512 + i];
  for (int i = t; i < 2 * MM; i += 1024)   posU[i] = outputs[4 * NB + i];
  if (t < 256) { int g = t >> 7, j = t & 127; hS[g][j] = 0.f; }
  if (t < HH) vS[t] = av[t];
  if (t < 254) actS[0][t] = t + 1;
  else if (t >= 512 && t < 766) actS[1][t - 512] = t - 511;
  if (t == 0) {
    cntS[0] = 254; curS[0] = bid;
    dstS[0][0] = outputs[2 * (NB + bid)]; dstS[0][1] = outputs[2 * (NB + bid) + 1];
  }
  if (t == 512) {
    cntS[1] = 254; curS[1] = bid + NBLK;
    dstS[1][0] = outputs[2 * (NB + bid + NBLK)];
    dstS[1][1] = outputs[2 * (NB + bid + NBLK) + 1];
  }
  __syncthreads();

  float px = 0.f, py = 0.f, md = 0.f;   // live in t==0 (g0) and t==512 (g1)
  if (t == 0)   { px = outputs[2 * bid];          py = outputs[2 * bid + 1]; }
  if (t == 512) { px = outputs[2 * (bid + NBLK)]; py = outputs[2 * (bid + NBLK) + 1]; }

  float creg = 0.f;                     // LSTM c-state, owned by t<256

  for (int k = 0; k < SS; ++k) {
    // ---- Phase A: EWi prefetch + gates partials.
    // Global rows kk = gh*32 + [0,32); LDS rows kk = 64 + gh*32 + [0,32).
    float4 ew4 = make_float4(0.f, 0.f, 0.f, 0.f);
    if (t < 256) ew4 = EWiP[(size_t)curS[t >> 7] * HH + (t & 127)];
    {
      const float* wg = Wh + (size_t)(gh * 32) * 512 + gj;
      const float* wl = &WhL[gh * 32][gj];
      float a0G = 0.f, a1G = 0.f, a0L = 0.f, a1L = 0.f;
      float wbuf0[16], wbuf1[16];
#pragma unroll
      for (int i = 0; i < 16; ++i) wbuf0[i] = wg[(size_t)i * 512];   // burst 1
      {
        const float4* hb0 = (const float4*)(&hS[0][64 + gh * 32]);
        const float4* hb1 = (const float4*)(&hS[1][64 + gh * 32]);
#pragma unroll
        for (int i = 0; i < 8; ++i) {                                 // LDS half
          float4 h0 = hb0[i], h1 = hb1[i];
          float wa = wl[(size_t)(4 * i) * 512];
          float wb = wl[(size_t)(4 * i + 1) * 512];
          float wc = wl[(size_t)(4 * i + 2) * 512];
          float wd = wl[(size_t)(4 * i + 3) * 512];
          a0L = fmaf(h0.x, wa, a0L); a0L = fmaf(h0.y, wb, a0L);
          a0L = fmaf(h0.z, wc, a0L); a0L = fmaf(h0.w, wd, a0L);
          a1L = fmaf(h1.x, wa, a1L); a1L = fmaf(h1.y, wb, a1L);
          a1L = fmaf(h1.z, wc, a1L); a1L = fmaf(h1.w, wd, a1L);
        }
      }
#pragma unroll
      for (int i = 0; i < 16; ++i) wbuf1[i] = wg[(size_t)(16 + i) * 512]; // burst 2
      {
        const float4* hb0 = (const float4*)(&hS[0][gh * 32]);
        const float4* hb1 = (const float4*)(&hS[1][gh * 32]);
#pragma unroll
        for (int i = 0; i < 4; ++i) {                                 // consume burst 1
          float4 h0 = hb0[i], h1 = hb1[i];
          a0G = fmaf(h0.x, wbuf0[4 * i],     a0G);
          a0G = fmaf(h0.y, wbuf0[4 * i + 1], a0G);
          a0G = fmaf(h0.z, wbuf0[4 * i + 2], a0G);
          a0G = fmaf(h0.w, wbuf0[4 * i + 3], a0G);
          a1G = fmaf(h1.x, wbuf0[4 * i],     a1G);
          a1G = fmaf(h1.y, wbuf0[4 * i + 1], a1G);
          a1G = fmaf(h1.z, wbuf0[4 * i + 2], a1G);
          a1G = fmaf(h1.w, wbuf0[4 * i + 3], a1G);
        }
#pragma unroll
        for (int i = 0; i < 4; ++i) {                                 // consume burst 2
          float4 h0 = hb0[4 + i], h1 = hb1[4 + i];
          a0G = fmaf(h0.x, wbuf1[4 * i],     a0G);
          a0G = fmaf(h0.y, wbuf1[4 * i + 1], a0G);
          a0G = fmaf(h0.z, wbuf1[4 * i + 2], a0G);
          a0G = fmaf(h0.w, wbuf1[4 * i + 3], a0G);
          a1G = fmaf(h1.x, wbuf1[4 * i],     a1G);
          a1G = fmaf(h1.y, wbuf1[4 * i + 1], a1G);
          a1G = fmaf(h1.z, wbuf1[4 * i + 2], a1G);
          a1G = fmaf(h1.w, wbuf1[4 * i + 3], a1G);
        }
      }
      pS[0][gh][gj] = a0G + a0L;
      pS[1][gh][gj] = a1G + a1L;
    }
    __syncthreads();  // B1

    // ---- Phase B: LSTM cell (t<256; order i,f,g,o)
    if (t < 256) {
      int g = t >> 7, jj = t & 127;
      float ei = ew4.x + (pS[g][0][jj]       + pS[g][1][jj]);
      float ef = ew4.y + (pS[g][0][128 + jj] + pS[g][1][128 + jj]);
      float eg = ew4.z + (pS[g][0][256 + jj] + pS[g][1][256 + jj]);
      float eo = ew4.w + (pS[g][0][384 + jj] + pS[g][1][384 + jj]);
      float iv = sigm(ei), fv = sigm(ef), gv = tanh_f(eg), ov = sigm(eo);
      float cn = fv * creg + iv * gv;
      creg = cn;
      hS[g][jj] = ov * tanh_f(cn);
    }
    __syncthreads();  // B2

    // ---- Phase C: q partials, 8 k-slices x 128 j, both g per thread
    {
      const float* wp = W2 + (size_t)(qq8 * 16) * HH + qj;
      const float4* h0 = (const float4*)(&hS[0][qq8 * 16]);
      const float4* h1 = (const float4*)(&hS[1][qq8 * 16]);
      float p0 = 0.f, p1 = 0.f;
#pragma unroll
      for (int i = 0; i < 4; ++i) {
        float4 hv0 = h0[i], hv1 = h1[i];
        float wa = wp[(size_t)(4 * i) * HH];
        float wb = wp[(size_t)(4 * i + 1) * HH];
        float wc = wp[(size_t)(4 * i + 2) * HH];
        float wd = wp[(size_t)(4 * i + 3) * HH];
        p0 = fmaf(hv0.x, wa, p0); p0 = fmaf(hv0.y, wb, p0);
        p0 = fmaf(hv0.z, wc, p0); p0 = fmaf(hv0.w, wd, p0);
        p1 = fmaf(hv1.x, wa, p1); p1 = fmaf(hv1.y, wb, p1);
        p1 = fmaf(hv1.z, wc, p1); p1 = fmaf(hv1.w, wd, p1);
      }
      qp[0][qq8][qj] = p0;
      qp[1][qq8][qj] = p1;
    }
    __syncthreads();  // B3

    // ---- Phase D: q reduce (t<256)
    if (t < 256) {
      int g = t >> 7, jj = t & 127;
      qS[g][jj] = ((qp[g][0][jj] + qp[g][1][jj]) + (qp[g][2][jj] + qp[g][3][jj]))
                + ((qp[g][4][jj] + qp[g][5][jj]) + (qp[g][6][jj] + qp[g][7][jj]));
    }
    __syncthreads();  // B4

    // ---- Phase E: logits over active nodes, 2-way h-split, float4 streams
    {
      int cnt = cntS[lg];
      int cntEff = cnt + (k > 0 ? 1 : 0);   // dst node re-enters for k>0
      if (lu < cntEff) {
        int s = (lu == cnt) ? 255 : actS[lg][lu];
        int r = (s == 255) ? (NB + bid + (lg << 8)) : (2 * NB + s - 1);
        const float4* wp = W1eQ + (size_t)(lhf * 16) * RTOT + r;
        const float4* qv4 = (const float4*)(&qS[lg][lhf * 64]);
        const float4* vv4 = (const float4*)(&vS[lhf * 64]);
        float c0 = 0.f, c1 = 0.f;
#pragma unroll 4
        for (int i = 0; i < 16; ++i) {
          float4 w = wp[(size_t)i * RTOT];
          float4 q = qv4[i];
          float4 v = vv4[i];
          c0 = fmaf(v.x, tanh_f(w.x + q.x), c0);
          c1 = fmaf(v.y, tanh_f(w.y + q.y), c1);
          c0 = fmaf(v.z, tanh_f(w.z + q.z), c0);
          c1 = fmaf(v.w, tanh_f(w.w + q.w), c1);
        }
        lp[lg][lhf][lu] = c0 + c1;
        if (lhf == 0) lsS[lg][lu] = s;
      }
    }
    __syncthreads();  // B5

    // ---- Phase F: argmax + state update (wave 0 -> g0, wave 8 -> g1)
    if ((t < 64) || (t >= 512 && t < 576)) {
      int g = t >> 9;
      int lane = t & 63;
      int cnt = cntS[g];
      int cntEff = cnt + (k > 0 ? 1 : 0);
      float val = -INFINITY;
      unsigned key = 0xFFFFFFFFu;
#pragma unroll
      for (int c = 0; c < 4; ++c) {
        int u = lane + 64 * c;
        if (u < cntEff) {
          float v2 = lp[g][0][u] + lp[g][1][u];
          unsigned k2 = ((unsigned)lsS[g][u] << 16) | (unsigned)u;
          if (v2 > val || (v2 == val && k2 < key)) { val = v2; key = k2; }
        }
      }
#pragma unroll
      for (int off = 1; off < 64; off <<= 1) {
        float v2 = __shfl_xor(val, off);
        unsigned k2 = __shfl_xor(key, off);
        if (v2 > val || (v2 == val && k2 < key)) { val = v2; key = k2; }
      }
      if (lane == 0) {
        int s   = (int)(key >> 16);
        int pos = (int)(key & 0xFFFFu);
        int rn  = (s == 255) ? (NB + bid + (g << 8)) : (2 * NB + s - 1);
        float nx, ny;
        if (s == 255) { nx = dstS[g][0]; ny = dstS[g][1]; }
        else          { nx = posU[2 * (s - 1)]; ny = posU[2 * (s - 1) + 1]; }
        float dx = nx - px, dy = ny - py;
        float d = sqrtf(dx * dx + dy * dy + 1e-12f);
        if (d > md) md = d;
        px = nx; py = ny;
        curS[g] = rn;
        if (s != 255) { actS[g][pos] = actS[g][cnt - 1]; cntS[g] = cnt - 1; }
      }
    }
    __syncthreads();  // B6
  }

  if (t == 0)   maxd_out[bid] = md;
  if (t == 512) maxd_out[bid + NBLK] = md;
}

__global__ __launch_bounds__(512) void reduce_k(const float* __restrict__ maxd,
                                               float* __restrict__ out)
{
  __shared__ float s[512];
  int t = threadIdx.x;
  s[t] = maxd[t];
  __syncthreads();
  for (int off = 256; off > 0; off >>= 1) {
    if (t < off) s[t] += s[t + off];
    __syncthreads();
  }
  if (t == 0) out[0] = s[0] * (1.0f / 512.0f);
}

extern "C" void kernel_launch(void* const* d_in, const int* in_sizes, int n_in,
                              void* d_out, int out_size, void* d_ws, size_t ws_size,
                              hipStream_t stream) {
  const float* outputs = (const float*)d_in[0];
  const float* Wemb    = (const float*)d_in[1];
  const float* bemb    = (const float*)d_in[2];
  const float* Wi      = (const float*)d_in[3];
  const float* Wh      = (const float*)d_in[4];
  const float* lb      = (const float*)d_in[5];
  const float* W1      = (const float*)d_in[6];
  const float* W2      = (const float*)d_in[7];
  const float* av      = (const float*)d_in[8];
  // d_in[9] = N (known constant 512)

  float* ws    = (float*)d_ws;
  float4* EWiP = (float4*)ws;                               // RTOT*128 float4
  float4* W1eQ = (float4*)(ws + (size_t)RTOT * 512);        // RTOT*32 float4
  float*  maxd = ws + (size_t)RTOT * 512 + (size_t)RTOT * 128;  // 512

  hipLaunchKernelGGL(precompute_k, dim3(RTOT), dim3(HH), 0, stream,
                     outputs, Wemb, bemb, Wi, W1, lb, EWiP, W1eQ);
  hipLaunchKernelGGL(decode_k, dim3(NBLK), dim3(1024), 0, stream,
                     outputs, Wh, W2, av, EWiP, W1eQ, maxd);
  hipLaunchKernelGGL(reduce_k, dim3(1), dim3(512), 0, stream, maxd, (float*)d_out);
}

// Round 12
// 2296.334 us; speedup vs baseline: 1.6715x; 1.3895x over previous
//
#include <hip/hip_runtime.h>
#include <math.h>

// Problem constants (fixed by reference file)
#define NB   512    // N = batch of user pairs
#define MM   254    // M uav nodes
#define SS   256    // S = M + 2 graph nodes per b
#define HH   128    // H hidden
#define RTOT 1278   // 2N + M rows in `outputs`
#define NBLK 256    // decode blocks; each handles b and b+256

#define C2   2.885390081777927f   // 2*log2(e): tanh arg pre-scale
#define C1   1.442695040888963f   // log2(e)

__device__ __forceinline__ float rcpf(float x)  { return __builtin_amdgcn_rcpf(x); }
__device__ __forceinline__ float exp2f_(float x){ return __builtin_amdgcn_exp2f(x); }
// sigmoid via exp2 + rcp (no div)
__device__ __forceinline__ float sigm2(float x)  { return rcpf(1.0f + exp2f_(-C1 * x)); }
// tanh via exp2 + rcp (no div)
__device__ __forceinline__ float tanh2(float x)  { return 1.0f - 2.0f * rcpf(1.0f + exp2f_(C2 * x)); }

// Per node row r: e = pos @ W_embed + b_embed (128),
//   EWiP[r][j]  = float4(i,f,g,o) columns of e@lstm_Wi + lstm_b (bias folded)
//   W1eQ[h4][r] = float4 of C2*W1e[4h4..4h4+3]  (pre-scaled, coalesced over r)
__global__ __launch_bounds__(128) void precompute_k(
    const float* __restrict__ outputs, const float* __restrict__ Wemb,
    const float* __restrict__ bemb, const float* __restrict__ Wi,
    const float* __restrict__ W1, const float* __restrict__ lb,
    float4* __restrict__ EWiP, float4* __restrict__ W1eQ)
{
  int r = blockIdx.x;
  int t = threadIdx.x;  // 128
  __shared__ float e[HH];
  __shared__ float w1e[HH];
  float px = outputs[2 * r], py = outputs[2 * r + 1];
  e[t] = px * Wemb[t] + py * Wemb[HH + t] + bemb[t];
  __syncthreads();
  float acc = 0.f;
#pragma unroll 8
  for (int h = 0; h < HH; ++h) acc = fmaf(e[h], W1[h * HH + t], acc);
  w1e[t] = acc;
  float g4[4];
#pragma unroll
  for (int c = 0; c < 4; ++c) {
    int j = t + c * HH;
    float a = 0.f;
#pragma unroll 8
    for (int h = 0; h < HH; ++h) a = fmaf(e[h], Wi[h * 512 + j], a);
    g4[c] = a + lb[j];
  }
  float4 v4; v4.x = g4[0]; v4.y = g4[1]; v4.z = g4[2]; v4.w = g4[3];
  EWiP[(size_t)r * HH + t] = v4;
  __syncthreads();
  if (t < 32) {
    float4 p;
    p.x = C2 * w1e[4 * t];     p.y = C2 * w1e[4 * t + 1];
    p.z = C2 * w1e[4 * t + 2]; p.w = C2 * w1e[4 * t + 3];
    W1eQ[(size_t)t * RTOT + r] = p;
  }
}

// WhT[512][128] = Wh^T, W2T[128][128] = W2^T (per-thread-row float4 reads)
__global__ __launch_bounds__(128) void transpose_k(
    const float* __restrict__ Wh, const float* __restrict__ W2,
    float* __restrict__ WhT, float* __restrict__ W2T)
{
  int bidx = blockIdx.x;  // 0..639
  int k = threadIdx.x;    // 0..127
  if (bidx < 512) WhT[(size_t)bidx * 128 + k] = Wh[(size_t)k * 512 + bidx];
  else {
    int j = bidx - 512;
    W2T[(size_t)j * 128 + k] = W2[(size_t)k * 128 + j];
  }
}

// One block per TWO batch elements (b, b+256). 1024 threads, grid 256.
// 5 phases/step: A(gates) | B(cell) | C(q, quad-shfl) | E(logits) | F(argmax).
__global__ __launch_bounds__(1024) void decode_k(
    const float* __restrict__ outputs, const float* __restrict__ WhT,
    const float* __restrict__ Wh, const float* __restrict__ W2T,
    const float* __restrict__ av,
    const float4* __restrict__ EWiP, const float4* __restrict__ W1eQ,
    float* __restrict__ maxd_out)
{
  const int t = threadIdx.x;   // 0..1023
  const int bid = blockIdx.x;

  __shared__ float WhL[64][512];            // 128 KB: Wh rows 64..127
  __shared__ float posU[2 * MM];            // uav node positions (2 KB)
  __shared__ float dstS[2][2];              // per-g dst node position
  __shared__ __align__(16) float hS[2][HH];
  __shared__ __align__(16) float qS[2][HH]; // pre-scaled by C2
  __shared__ __align__(16) float vS2[HH];   // -2*av
  __shared__ float sumvS[2];                // per-half sum of av
  __shared__ float pS[2][2][512];           // gates partials [g][gh][j]
  __shared__ float lp[2][2][SS];            // logit partials [g][hhalf][u]
  __shared__ int   lsS[2][SS];              // node id s per slot u
  __shared__ int   actS[2][254];
  __shared__ int   cntS[2], curS[2];

  const int gj  = t >> 1;        // gates column (pair-interleaved)
  const int gh  = t & 1;         // gates k-half (0/1)
  const int cg  = t >> 9;        // q batch slot
  const int cj  = (t >> 2) & 127;// q column
  const int ckq = t & 3;         // q k-quarter
  const int lg  = t >> 9;        // logits batch slot
  const int lhf = (t >> 8) & 1;  // logits h-half
  const int lu  = t & 255;       // logits node slot

  // ---- init ----
  for (int i = t; i < 64 * 512; i += 1024) ((float*)WhL)[i] = Wh[64 * 512 + i];
  for (int i = t; i < 2 * MM; i += 1024)   posU[i] = outputs[4 * NB + i];
  if (t < 256) { int g = t >> 7, j = t & 127; hS[g][j] = 0.f; }
  if (t < HH) vS2[t] = -2.0f * av[t];
  if (t >= 256 && t < 258) {
    int half = t - 256; float s = 0.f;
    for (int h = half * 64; h < half * 64 + 64; ++h) s += av[h];
    sumvS[half] = s;
  }
  if (t < 254) actS[0][t] = t + 1;
  else if (t >= 512 && t < 766) actS[1][t - 512] = t - 511;
  if (t == 0) {
    cntS[0] = 254; curS[0] = bid;
    dstS[0][0] = outputs[2 * (NB + bid)]; dstS[0][1] = outputs[2 * (NB + bid) + 1];
  }
  if (t == 512) {
    cntS[1] = 254; curS[1] = bid + NBLK;
    dstS[1][0] = outputs[2 * (NB + bid + NBLK)];
    dstS[1][1] = outputs[2 * (NB + bid + NBLK) + 1];
  }
  __syncthreads();

  float px = 0.f, py = 0.f, md = 0.f;   // live in t==0 (g0) and t==512 (g1)
  if (t == 0)   { px = outputs[2 * bid];          py = outputs[2 * bid + 1]; }
  if (t == 512) { px = outputs[2 * (bid + NBLK)]; py = outputs[2 * (bid + NBLK) + 1]; }

  float creg = 0.f;                     // LSTM c-state, owned by t<256

  for (int k = 0; k < SS; ++k) {
    // ---- Phase A: EWi prefetch + gates partials.
    // Thread (gj, gh): global k in gh*32+[0,32) via WhT row (8 float4),
    // LDS k in 64+gh*32+[0,32) via WhL scalar. Both g per thread.
    float4 ew4 = make_float4(0.f, 0.f, 0.f, 0.f);
    if (t < 256) ew4 = EWiP[(size_t)curS[t >> 7] * HH + (t & 127)];
    {
      const float4* wg4 = (const float4*)(WhT + (size_t)gj * 128 + gh * 32);
      float4 wb[8];
#pragma unroll
      for (int i = 0; i < 8; ++i) wb[i] = wg4[i];        // 8 loads in flight
      float a0G = 0.f, a1G = 0.f, a0L = 0.f, a1L = 0.f;
      {
        const float* wl = &WhL[gh * 32][gj];
        const float4* hb0 = (const float4*)(&hS[0][64 + gh * 32]);
        const float4* hb1 = (const float4*)(&hS[1][64 + gh * 32]);
#pragma unroll
        for (int i = 0; i < 8; ++i) {                     // LDS half
          float4 h0 = hb0[i], h1 = hb1[i];
          float wa = wl[(size_t)(4 * i) * 512];
          float wbv = wl[(size_t)(4 * i + 1) * 512];
          float wc = wl[(size_t)(4 * i + 2) * 512];
          float wd = wl[(size_t)(4 * i + 3) * 512];
          a0L = fmaf(h0.x, wa, a0L); a0L = fmaf(h0.y, wbv, a0L);
          a0L = fmaf(h0.z, wc, a0L); a0L = fmaf(h0.w, wd, a0L);
          a1L = fmaf(h1.x, wa, a1L); a1L = fmaf(h1.y, wbv, a1L);
          a1L = fmaf(h1.z, wc, a1L); a1L = fmaf(h1.w, wd, a1L);
        }
      }
      {
        const float4* hb0 = (const float4*)(&hS[0][gh * 32]);
        const float4* hb1 = (const float4*)(&hS[1][gh * 32]);
#pragma unroll
        for (int i = 0; i < 8; ++i) {                     // global half
          float4 h0 = hb0[i], h1 = hb1[i];
          float4 w = wb[i];
          a0G = fmaf(h0.x, w.x, a0G); a0G = fmaf(h0.y, w.y, a0G);
          a0G = fmaf(h0.z, w.z, a0G); a0G = fmaf(h0.w, w.w, a0G);
          a1G = fmaf(h1.x, w.x, a1G); a1G = fmaf(h1.y, w.y, a1G);
          a1G = fmaf(h1.z, w.z, a1G); a1G = fmaf(h1.w, w.w, a1G);
        }
      }
      pS[0][gh][gj] = a0G + a0L;
      pS[1][gh][gj] = a1G + a1L;
    }
    __syncthreads();  // B1

    // ---- Phase B: LSTM cell (t<256; order i,f,g,o) — div-free forms
    if (t < 256) {
      int g = t >> 7, jj = t & 127;
      float ei = ew4.x + (pS[g][0][jj]       + pS[g][1][jj]);
      float ef = ew4.y + (pS[g][0][128 + jj] + pS[g][1][128 + jj]);
      float eg = ew4.z + (pS[g][0][256 + jj] + pS[g][1][256 + jj]);
      float eo = ew4.w + (pS[g][0][384 + jj] + pS[g][1][384 + jj]);
      float iv = sigm2(ei), fv = sigm2(ef), gv = tanh2(eg), ov = sigm2(eo);
      float cn = fv * creg + iv * gv;
      creg = cn;
      hS[g][jj] = ov * tanh2(cn);
    }
    __syncthreads();  // B2

    // ---- Phase C: q[g][j], quad k-split + shfl reduce. Thread (cg,cj,ckq):
    // W2T row cj, k in ckq*32+[0,32): 8 float4, quad-contiguous (coalesced).
    {
      const float4* w4 = (const float4*)(W2T + (size_t)cj * 128 + ckq * 32);
      const float4* h4 = (const float4*)(&hS[cg][ckq * 32]);
      float p0 = 0.f, p1 = 0.f;
#pragma unroll
      for (int i = 0; i < 8; ++i) {
        float4 w = w4[i], h = h4[i];
        p0 = fmaf(h.x, w.x, p0); p1 = fmaf(h.y, w.y, p1);
        p0 = fmaf(h.z, w.z, p0); p1 = fmaf(h.w, w.w, p1);
      }
      float p = p0 + p1;
      p += __shfl_xor(p, 1);
      p += __shfl_xor(p, 2);
      if (ckq == 0) qS[cg][cj] = C2 * p;   // pre-scaled for exp2
    }
    __syncthreads();  // B3

    // ---- Phase E: logits over active nodes; fused tanh:
    // logit = sum(v) + sum((-2v) * rcp(1 + 2^(w' + q')))  [w',q' pre-scaled]
    {
      int cnt = cntS[lg];
      int cntEff = cnt + (k > 0 ? 1 : 0);   // dst node re-enters for k>0
      if (lu < cntEff) {
        int s = (lu == cnt) ? 255 : actS[lg][lu];
        int r = (s == 255) ? (NB + bid + (lg << 8)) : (2 * NB + s - 1);
        const float4* wp = W1eQ + (size_t)(lhf * 16) * RTOT + r;
        const float4* qv4 = (const float4*)(&qS[lg][lhf * 64]);
        const float4* vv4 = (const float4*)(&vS2[lhf * 64]);
        float c0 = 0.f, c1 = 0.f;
#pragma unroll 4
        for (int i = 0; i < 16; ++i) {
          float4 w = wp[(size_t)i * RTOT];
          float4 q = qv4[i];
          float4 v = vv4[i];
          c0 = fmaf(v.x, rcpf(1.0f + exp2f_(w.x + q.x)), c0);
          c1 = fmaf(v.y, rcpf(1.0f + exp2f_(w.y + q.y)), c1);
          c0 = fmaf(v.z, rcpf(1.0f + exp2f_(w.z + q.z)), c0);
          c1 = fmaf(v.w, rcpf(1.0f + exp2f_(w.w + q.w)), c1);
        }
        lp[lg][lhf][lu] = (c0 + c1) + sumvS[lhf];
        if (lhf == 0) lsS[lg][lu] = s;
      }
    }
    __syncthreads();  // B4

    // ---- Phase F: argmax + state update (wave 0 -> g0, wave 8 -> g1)
    if ((t < 64) || (t >= 512 && t < 576)) {
      int g = t >> 9;
      int lane = t & 63;
      int cnt = cntS[g];
      int cntEff = cnt + (k > 0 ? 1 : 0);
      float val = -INFINITY;
      unsigned key = 0xFFFFFFFFu;
#pragma unroll
      for (int c = 0; c < 4; ++c) {
        int u = lane + 64 * c;
        if (u < cntEff) {
          float v2 = lp[g][0][u] + lp[g][1][u];
          unsigned k2 = ((unsigned)lsS[g][u] << 16) | (unsigned)u;
          if (v2 > val || (v2 == val && k2 < key)) { val = v2; key = k2; }
        }
      }
#pragma unroll
      for (int off = 1; off < 64; off <<= 1) {
        float v2 = __shfl_xor(val, off);
        unsigned k2 = __shfl_xor(key, off);
        if (v2 > val || (v2 == val && k2 < key)) { val = v2; key = k2; }
      }
      if (lane == 0) {
        int s   = (int)(key >> 16);
        int pos = (int)(key & 0xFFFFu);
        int rn  = (s == 255) ? (NB + bid + (g << 8)) : (2 * NB + s - 1);
        float nx, ny;
        if (s == 255) { nx = dstS[g][0]; ny = dstS[g][1]; }
        else          { nx = posU[2 * (s - 1)]; ny = posU[2 * (s - 1) + 1]; }
        float dx = nx - px, dy = ny - py;
        float d = sqrtf(dx * dx + dy * dy + 1e-12f);
        if (d > md) md = d;
        px = nx; py = ny;
        curS[g] = rn;
        if (s != 255) { actS[g][pos] = actS[g][cnt - 1]; cntS[g] = cnt - 1; }
      }
    }
    __syncthreads();  // B5
  }

  if (t == 0)   maxd_out[bid] = md;
  if (t == 512) maxd_out[bid + NBLK] = md;
}

__global__ __launch_bounds__(512) void reduce_k(const float* __restrict__ maxd,
                                               float* __restrict__ out)
{
  __shared__ float s[512];
  int t = threadIdx.x;
  s[t] = maxd[t];
  __syncthreads();
  for (int off = 256; off > 0; off >>= 1) {
    if (t < off) s[t] += s[t + off];
    __syncthreads();
  }
  if (t == 0) out[0] = s[0] * (1.0f / 512.0f);
}

extern "C" void kernel_launch(void* const* d_in, const int* in_sizes, int n_in,
                              void* d_out, int out_size, void* d_ws, size_t ws_size,
                              hipStream_t stream) {
  const float* outputs = (const float*)d_in[0];
  const float* Wemb    = (const float*)d_in[1];
  const float* bemb    = (const float*)d_in[2];
  const float* Wi      = (const float*)d_in[3];
  const float* Wh      = (const float*)d_in[4];
  const float* lb      = (const float*)d_in[5];
  const float* W1      = (const float*)d_in[6];
  const float* W2      = (const float*)d_in[7];
  const float* av      = (const float*)d_in[8];
  // d_in[9] = N (known constant 512)

  float* ws    = (float*)d_ws;
  float4* EWiP = (float4*)ws;                               // RTOT*128 float4
  float4* W1eQ = (float4*)(ws + (size_t)RTOT * 512);        // RTOT*32 float4
  float*  WhT  = ws + (size_t)RTOT * 512 + (size_t)RTOT * 128;   // 512*128
  float*  W2T  = WhT + (size_t)512 * 128;                   // 128*128
  float*  maxd = W2T + (size_t)128 * 128;                   // 512

  hipLaunchKernelGGL(transpose_k, dim3(640), dim3(128), 0, stream, Wh, W2, WhT, W2T);
  hipLaunchKernelGGL(precompute_k, dim3(RTOT), dim3(HH), 0, stream,
                     outputs, Wemb, bemb, Wi, W1, lb, EWiP, W1eQ);
  hipLaunchKernelGGL(decode_k, dim3(NBLK), dim3(1024), 0, stream,
                     outputs, WhT, Wh, W2T, av, EWiP, W1eQ, maxd);
  hipLaunchKernelGGL(reduce_k, dim3(1), dim3(512), 0, stream, maxd, (float*)d_out);
}

// Round 13
// 2178.790 us; speedup vs baseline: 1.7617x; 1.0539x over previous
//
#include <hip/hip_runtime.h>
#include <math.h>

// Problem constants (fixed by reference file)
#define NB   512    // N = batch of user pairs
#define MM   254    // M uav nodes
#define SS   256    // S = M + 2 graph nodes per b
#define HH   128    // H hidden
#define RTOT 1278   // 2N + M rows in `outputs`
#define NBLK 256    // decode blocks; each handles b and b+256

#define C2   2.885390081777927f   // 2*log2(e): tanh arg pre-scale
#define C1   1.442695040888963f   // log2(e)

__device__ __forceinline__ float rcpf(float x)  { return __builtin_amdgcn_rcpf(x); }
__device__ __forceinline__ float exp2f_(float x){ return __builtin_amdgcn_exp2f(x); }
// sigmoid via exp2 + rcp (no div)
__device__ __forceinline__ float sigm2(float x)  { return rcpf(1.0f + exp2f_(-C1 * x)); }
// tanh via exp2 + rcp (no div)
__device__ __forceinline__ float tanh2(float x)  { return 1.0f - 2.0f * rcpf(1.0f + exp2f_(C2 * x)); }

// Per node row r: e = pos @ W_embed + b_embed (128),
//   EWiP[r][j]  = float4(i,f,g,o) columns of e@lstm_Wi + lstm_b (bias folded)
//   W1eQ[h4][r] = float4 of C2*W1e[4h4..4h4+3]  (pre-scaled, coalesced over r)
__global__ __launch_bounds__(128) void precompute_k(
    const float* __restrict__ outputs, const float* __restrict__ Wemb,
    const float* __restrict__ bemb, const float* __restrict__ Wi,
    const float* __restrict__ W1, const float* __restrict__ lb,
    float4* __restrict__ EWiP, float4* __restrict__ W1eQ)
{
  int r = blockIdx.x;
  int t = threadIdx.x;  // 128
  __shared__ float e[HH];
  __shared__ float w1e[HH];
  float px = outputs[2 * r], py = outputs[2 * r + 1];
  e[t] = px * Wemb[t] + py * Wemb[HH + t] + bemb[t];
  __syncthreads();
  float acc = 0.f;
#pragma unroll 8
  for (int h = 0; h < HH; ++h) acc = fmaf(e[h], W1[h * HH + t], acc);
  w1e[t] = acc;
  float g4[4];
#pragma unroll
  for (int c = 0; c < 4; ++c) {
    int j = t + c * HH;
    float a = 0.f;
#pragma unroll 8
    for (int h = 0; h < HH; ++h) a = fmaf(e[h], Wi[h * 512 + j], a);
    g4[c] = a + lb[j];
  }
  float4 v4; v4.x = g4[0]; v4.y = g4[1]; v4.z = g4[2]; v4.w = g4[3];
  EWiP[(size_t)r * HH + t] = v4;
  __syncthreads();
  if (t < 32) {
    float4 p;
    p.x = C2 * w1e[4 * t];     p.y = C2 * w1e[4 * t + 1];
    p.z = C2 * w1e[4 * t + 2]; p.w = C2 * w1e[4 * t + 3];
    W1eQ[(size_t)t * RTOT + r] = p;
  }
}

// WhT[512][128] = Wh^T, W2T[128][128] = W2^T (per-thread-row float4 reads)
__global__ __launch_bounds__(128) void transpose_k(
    const float* __restrict__ Wh, const float* __restrict__ W2,
    float* __restrict__ WhT, float* __restrict__ W2T)
{
  int bidx = blockIdx.x;  // 0..639
  int k = threadIdx.x;    // 0..127
  if (bidx < 512) WhT[(size_t)bidx * 128 + k] = Wh[(size_t)k * 512 + bidx];
  else {
    int j = bidx - 512;
    W2T[(size_t)j * 128 + k] = W2[(size_t)k * 128 + j];
  }
}

// One block per TWO batch elements (b, b+256). 1024 threads, grid 256.
// 149 KB LDS -> exactly 1 block/CU (4 waves/EU) -> 128-VGPR budget, so the
// per-thread Wh global half (whreg[8] float4) is genuinely register-resident.
// Bank-conflict-free mapping: gh uniform per 32-lane group, gj distinct mod 32.
__global__ __attribute__((amdgpu_waves_per_eu(4, 4)))
__launch_bounds__(1024) void decode_k(
    const float* __restrict__ outputs, const float* __restrict__ WhT,
    const float* __restrict__ Wh, const float* __restrict__ W2T,
    const float* __restrict__ av,
    const float4* __restrict__ EWiP, const float4* __restrict__ W1eQ,
    float* __restrict__ maxd_out)
{
  const int t = threadIdx.x;   // 0..1023
  const int bid = blockIdx.x;

  __shared__ float WhL[64][512];            // 128 KB: Wh rows 64..127
  __shared__ float posU[2 * MM];            // uav node positions (2 KB)
  __shared__ float dstS[2][2];              // per-g dst node position
  __shared__ __align__(16) float hS[2][HH];
  __shared__ __align__(16) float qS[2][HH]; // pre-scaled by C2
  __shared__ __align__(16) float vS2[HH];   // -2*av
  __shared__ float sumvS[2];                // per-half sum of av
  __shared__ float pS[2][2][512];           // gates partials [g][gh][j]
  __shared__ float lp[2][2][SS];            // logit partials [g][hhalf][u]
  __shared__ int   lsS[2][SS];              // node id s per slot u
  __shared__ int   actS[2][254];
  __shared__ int   cntS[2], curS[2];

  // Bank-conflict-free gates mapping: within each 32-lane group gh is
  // uniform and gj covers 32 consecutive values (banks 0..31 distinct).
  const int gh  = (t >> 5) & 1;            // gates k-half (0/1)
  const int gj  = ((t >> 6) << 5) | (t & 31);  // gates column, 0..511
  const int cg  = t >> 9;        // q batch slot
  const int cj  = (t >> 2) & 127;// q column
  const int ckq = t & 3;         // q k-quarter
  const int lg  = t >> 9;        // logits batch slot
  const int lhf = (t >> 8) & 1;  // logits h-half
  const int lu  = t & 255;       // logits node slot

  // ---- persistent register-resident Wh global half (k in gh*32+[0,32)) ----
  float4 whreg[8];
  {
    const float4* wg4 = (const float4*)(WhT + (size_t)gj * 128 + gh * 32);
#pragma unroll
    for (int i = 0; i < 8; ++i) whreg[i] = wg4[i];
  }

  // ---- init ----
  for (int i = t; i < 64 * 512; i += 1024) ((float*)WhL)[i] = Wh[64 * 512 + i];
  for (int i = t; i < 2 * MM; i += 1024)   posU[i] = outputs[4 * NB + i];
  if (t < 256) { int g = t >> 7, j = t & 127; hS[g][j] = 0.f; }
  if (t < HH) vS2[t] = -2.0f * av[t];
  if (t >= 256 && t < 258) {
    int half = t - 256; float s = 0.f;
    for (int h = half * 64; h < half * 64 + 64; ++h) s += av[h];
    sumvS[half] = s;
  }
  if (t < 254) actS[0][t] = t + 1;
  else if (t >= 512 && t < 766) actS[1][t - 512] = t - 511;
  if (t == 0) {
    cntS[0] = 254; curS[0] = bid;
    dstS[0][0] = outputs[2 * (NB + bid)]; dstS[0][1] = outputs[2 * (NB + bid) + 1];
  }
  if (t == 512) {
    cntS[1] = 254; curS[1] = bid + NBLK;
    dstS[1][0] = outputs[2 * (NB + bid + NBLK)];
    dstS[1][1] = outputs[2 * (NB + bid + NBLK) + 1];
  }
  __syncthreads();

  float px = 0.f, py = 0.f, md = 0.f;   // live in t==0 (g0) and t==512 (g1)
  if (t == 0)   { px = outputs[2 * bid];          py = outputs[2 * bid + 1]; }
  if (t == 512) { px = outputs[2 * (bid + NBLK)]; py = outputs[2 * (bid + NBLK) + 1]; }

  float creg = 0.f;                     // LSTM c-state, owned by t<256

  for (int k = 0; k < SS; ++k) {
    // ---- Phase A: EWi prefetch + gates partials.
    // Thread (gj, gh): k in gh*32+[0,32) from whreg (registers),
    // k in 64+gh*32+[0,32) from WhL (LDS, conflict-free). Both g per thread.
    float4 ew4 = make_float4(0.f, 0.f, 0.f, 0.f);
    if (t < 256) ew4 = EWiP[(size_t)curS[t >> 7] * HH + (t & 127)];
    {
      float a0G = 0.f, a1G = 0.f, a0L = 0.f, a1L = 0.f;
      {
        const float* wl = &WhL[gh * 32][gj];
        const float4* hb0 = (const float4*)(&hS[0][64 + gh * 32]);
        const float4* hb1 = (const float4*)(&hS[1][64 + gh * 32]);
#pragma unroll
        for (int i = 0; i < 8; ++i) {                     // LDS half
          float4 h0 = hb0[i], h1 = hb1[i];
          float wa = wl[(size_t)(4 * i) * 512];
          float wbv = wl[(size_t)(4 * i + 1) * 512];
          float wc = wl[(size_t)(4 * i + 2) * 512];
          float wd = wl[(size_t)(4 * i + 3) * 512];
          a0L = fmaf(h0.x, wa, a0L); a0L = fmaf(h0.y, wbv, a0L);
          a0L = fmaf(h0.z, wc, a0L); a0L = fmaf(h0.w, wd, a0L);
          a1L = fmaf(h1.x, wa, a1L); a1L = fmaf(h1.y, wbv, a1L);
          a1L = fmaf(h1.z, wc, a1L); a1L = fmaf(h1.w, wd, a1L);
        }
      }
      {
        const float4* hb0 = (const float4*)(&hS[0][gh * 32]);
        const float4* hb1 = (const float4*)(&hS[1][gh * 32]);
#pragma unroll
        for (int i = 0; i < 8; ++i) {                     // register half
          float4 h0 = hb0[i], h1 = hb1[i];
          float4 w = whreg[i];
          a0G = fmaf(h0.x, w.x, a0G); a0G = fmaf(h0.y, w.y, a0G);
          a0G = fmaf(h0.z, w.z, a0G); a0G = fmaf(h0.w, w.w, a0G);
          a1G = fmaf(h1.x, w.x, a1G); a1G = fmaf(h1.y, w.y, a1G);
          a1G = fmaf(h1.z, w.z, a1G); a1G = fmaf(h1.w, w.w, a1G);
        }
      }
      pS[0][gh][gj] = a0G + a0L;
      pS[1][gh][gj] = a1G + a1L;
    }
    __syncthreads();  // B1

    // ---- Phase B: LSTM cell (t<256; order i,f,g,o) — div-free forms
    if (t < 256) {
      int g = t >> 7, jj = t & 127;
      float ei = ew4.x + (pS[g][0][jj]       + pS[g][1][jj]);
      float ef = ew4.y + (pS[g][0][128 + jj] + pS[g][1][128 + jj]);
      float eg = ew4.z + (pS[g][0][256 + jj] + pS[g][1][256 + jj]);
      float eo = ew4.w + (pS[g][0][384 + jj] + pS[g][1][384 + jj]);
      float iv = sigm2(ei), fv = sigm2(ef), gv = tanh2(eg), ov = sigm2(eo);
      float cn = fv * creg + iv * gv;
      creg = cn;
      hS[g][jj] = ov * tanh2(cn);
    }
    __syncthreads();  // B2

    // ---- Phase C: q[g][j], quad k-split + shfl reduce. Thread (cg,cj,ckq):
    // W2T row cj, k in ckq*32+[0,32): 8 float4, quad-contiguous (coalesced).
    {
      const float4* w4 = (const float4*)(W2T + (size_t)cj * 128 + ckq * 32);
      const float4* h4 = (const float4*)(&hS[cg][ckq * 32]);
      float p0 = 0.f, p1 = 0.f;
#pragma unroll
      for (int i = 0; i < 8; ++i) {
        float4 w = w4[i], h = h4[i];
        p0 = fmaf(h.x, w.x, p0); p1 = fmaf(h.y, w.y, p1);
        p0 = fmaf(h.z, w.z, p0); p1 = fmaf(h.w, w.w, p1);
      }
      float p = p0 + p1;
      p += __shfl_xor(p, 1);
      p += __shfl_xor(p, 2);
      if (ckq == 0) qS[cg][cj] = C2 * p;   // pre-scaled for exp2
    }
    __syncthreads();  // B3

    // ---- Phase E: logits over active nodes; fused tanh:
    // logit = sum(v) + sum((-2v) * rcp(1 + 2^(w' + q')))  [w',q' pre-scaled]
    {
      int cnt = cntS[lg];
      int cntEff = cnt + (k > 0 ? 1 : 0);   // dst node re-enters for k>0
      if (lu < cntEff) {
        int s = (lu == cnt) ? 255 : actS[lg][lu];
        int r = (s == 255) ? (NB + bid + (lg << 8)) : (2 * NB + s - 1);
        const float4* wp = W1eQ + (size_t)(lhf * 16) * RTOT + r;
        const float4* qv4 = (const float4*)(&qS[lg][lhf * 64]);
        const float4* vv4 = (const float4*)(&vS2[lhf * 64]);
        float c0 = 0.f, c1 = 0.f;
#pragma unroll 4
        for (int i = 0; i < 16; ++i) {
          float4 w = wp[(size_t)i * RTOT];
          float4 q = qv4[i];
          float4 v = vv4[i];
          c0 = fmaf(v.x, rcpf(1.0f + exp2f_(w.x + q.x)), c0);
          c1 = fmaf(v.y, rcpf(1.0f + exp2f_(w.y + q.y)), c1);
          c0 = fmaf(v.z, rcpf(1.0f + exp2f_(w.z + q.z)), c0);
          c1 = fmaf(v.w, rcpf(1.0f + exp2f_(w.w + q.w)), c1);
        }
        lp[lg][lhf][lu] = (c0 + c1) + sumvS[lhf];
        if (lhf == 0) lsS[lg][lu] = s;
      }
    }
    __syncthreads();  // B4

    // ---- Phase F: argmax + state update (wave 0 -> g0, wave 8 -> g1)
    if ((t < 64) || (t >= 512 && t < 576)) {
      int g = t >> 9;
      int lane = t & 63;
      int cnt = cntS[g];
      int cntEff = cnt + (k > 0 ? 1 : 0);
      float val = -INFINITY;
      unsigned key = 0xFFFFFFFFu;
#pragma unroll
      for (int c = 0; c < 4; ++c) {
        int u = lane + 64 * c;
        if (u < cntEff) {
          float v2 = lp[g][0][u] + lp[g][1][u];
          unsigned k2 = ((unsigned)lsS[g][u] << 16) | (unsigned)u;
          if (v2 > val || (v2 == val && k2 < key)) { val = v2; key = k2; }
        }
      }
#pragma unroll
      for (int off = 1; off < 64; off <<= 1) {
        float v2 = __shfl_xor(val, off);
        unsigned k2 = __shfl_xor(key, off);
        if (v2 > val || (v2 == val && k2 < key)) { val = v2; key = k2; }
      }
      if (lane == 0) {
        int s   = (int)(key >> 16);
        int pos = (int)(key & 0xFFFFu);
        int rn  = (s == 255) ? (NB + bid + (g << 8)) : (2 * NB + s - 1);
        float nx, ny;
        if (s == 255) { nx = dstS[g][0]; ny = dstS[g][1]; }
        else          { nx = posU[2 * (s - 1)]; ny = posU[2 * (s - 1) + 1]; }
        float dx = nx - px, dy = ny - py;
        float d = sqrtf(dx * dx + dy * dy + 1e-12f);
        if (d > md) md = d;
        px = nx; py = ny;
        curS[g] = rn;
        if (s != 255) { actS[g][pos] = actS[g][cnt - 1]; cntS[g] = cnt - 1; }
      }
    }
    __syncthreads();  // B5
  }

  if (t == 0)   maxd_out[bid] = md;
  if (t == 512) maxd_out[bid + NBLK] = md;
}

__global__ __launch_bounds__(512) void reduce_k(const float* __restrict__ maxd,
                                               float* __restrict__ out)
{
  __shared__ float s[512];
  int t = threadIdx.x;
  s[t] = maxd[t];
  __syncthreads();
  for (int off = 256; off > 0; off >>= 1) {
    if (t < off) s[t] += s[t + off];
    __syncthreads();
  }
  if (t == 0) out[0] = s[0] * (1.0f / 512.0f);
}

extern "C" void kernel_launch(void* const* d_in, const int* in_sizes, int n_in,
                              void* d_out, int out_size, void* d_ws, size_t ws_size,
                              hipStream_t stream) {
  const float* outputs = (const float*)d_in[0];
  const float* Wemb    = (const float*)d_in[1];
  const float* bemb    = (const float*)d_in[2];
  const float* Wi      = (const float*)d_in[3];
  const float* Wh      = (const float*)d_in[4];
  const float* lb      = (const float*)d_in[5];
  const float* W1      = (const float*)d_in[6];
  const float* W2      = (const float*)d_in[7];
  const float* av      = (const float*)d_in[8];
  // d_in[9] = N (known constant 512)

  float* ws    = (float*)d_ws;
  float4* EWiP = (float4*)ws;                               // RTOT*128 float4
  float4* W1eQ = (float4*)(ws + (size_t)RTOT * 512);        // RTOT*32 float4
  float*  WhT  = ws + (size_t)RTOT * 512 + (size_t)RTOT * 128;   // 512*128
  float*  W2T  = WhT + (size_t)512 * 128;                   // 128*128
  float*  maxd = W2T + (size_t)128 * 128;                   // 512

  hipLaunchKernelGGL(transpose_k, dim3(640), dim3(128), 0, stream, Wh, W2, WhT, W2T);
  hipLaunchKernelGGL(precompute_k, dim3(RTOT), dim3(HH), 0, stream,
                     outputs, Wemb, bemb, Wi, W1, lb, EWiP, W1eQ);
  hipLaunchKernelGGL(decode_k, dim3(NBLK), dim3(1024), 0, stream,
                     outputs, WhT, Wh, W2T, av, EWiP, W1eQ, maxd);
  hipLaunchKernelGGL(reduce_k, dim3(1), dim3(512), 0, stream, maxd, (float*)d_out);
}